// Round 1
// baseline (241.651 us; speedup 1.0000x reference)
//
#include <hip/hip_runtime.h>
#include <hip/hip_bf16.h>

typedef __attribute__((ext_vector_type(8))) short bf16x8;
typedef __attribute__((ext_vector_type(4))) float f32x4;

static __device__ __forceinline__ unsigned short f2bf(float f) {
    unsigned u = __builtin_bit_cast(unsigned, f);
    unsigned rounding = 0x7fffu + ((u >> 16) & 1u);
    u += rounding;
    return (unsigned short)(u >> 16);
}

static __device__ __forceinline__ void async_copy16(const void* g, void* l) {
    __builtin_amdgcn_global_load_lds(
        (const __attribute__((address_space(1))) unsigned int*)g,
        (__attribute__((address_space(3))) unsigned int*)l,
        16, 0, 0);
}

// ---------------- LayerNorm (fp32) -> bf16 cast ----------------
// one block per row, 256 threads, 4 elems/thread (H=1024)
__global__ __launch_bounds__(256) void ln_cast_kernel(
    const float* __restrict__ x, const float* __restrict__ gamma,
    const float* __restrict__ beta, unsigned short* __restrict__ out) {
    const int row = blockIdx.x;
    const int t = threadIdx.x;
    const float4 v = ((const float4*)(x + (size_t)row * 1024))[t];

    float s  = v.x + v.y + v.z + v.w;
    float ss = v.x * v.x + v.y * v.y + v.z * v.z + v.w * v.w;
    #pragma unroll
    for (int off = 32; off; off >>= 1) {
        s  += __shfl_down(s, off);
        ss += __shfl_down(ss, off);
    }
    __shared__ float red[8];
    const int wid = t >> 6, lane = t & 63;
    if (lane == 0) { red[wid] = s; red[wid + 4] = ss; }
    __syncthreads();
    if (t == 0) {
        float S  = red[0] + red[1] + red[2] + red[3];
        float SS = red[4] + red[5] + red[6] + red[7];
        float mu = S * (1.0f / 1024.0f);
        float var = SS * (1.0f / 1024.0f) - mu * mu;
        red[0] = mu;
        red[1] = rsqrtf(var + 1e-7f);
    }
    __syncthreads();
    const float mu = red[0], rs = red[1];
    const float4 g = ((const float4*)gamma)[t];
    const float4 b = ((const float4*)beta)[t];

    ushort4 pk;
    pk.x = f2bf((v.x - mu) * rs * g.x + b.x);
    pk.y = f2bf((v.y - mu) * rs * g.y + b.y);
    pk.z = f2bf((v.z - mu) * rs * g.z + b.z);
    pk.w = f2bf((v.w - mu) * rs * g.w + b.w);
    ((ushort4*)(out + (size_t)row * 1024))[t] = pk;
}

// ---------------- W [1024][4096] fp32 -> Wt [4096][1024] bf16 ----------------
__global__ __launch_bounds__(256) void wt_cast_kernel(
    const float* __restrict__ W, unsigned short* __restrict__ Wt) {
    __shared__ float tile[32][33];
    const int bx = blockIdx.x;  // n tile (4096/32 = 128)
    const int by = blockIdx.y;  // k tile (1024/32 = 32)
    const int tx = threadIdx.x & 31;
    const int ty = threadIdx.x >> 5;  // 0..7
    #pragma unroll
    for (int i = 0; i < 4; ++i) {
        int k = by * 32 + ty + i * 8;
        tile[ty + i * 8][tx] = W[(size_t)k * 4096 + bx * 32 + tx];
    }
    __syncthreads();
    #pragma unroll
    for (int i = 0; i < 4; ++i) {
        int n = bx * 32 + ty + i * 8;
        Wt[(size_t)n * 1024 + by * 32 + tx] = f2bf(tile[tx][ty + i * 8]);
    }
}

// ---------------- GEMM: out[16384][4096] = gelu(A_bf16 @ Wt_bf16^T + bias) ----------------
// A: [16384][1024] bf16 row-major; Wt: [4096][1024] bf16 row-major (= W^T)
// 128x128 tile, BK=64, 4 waves (2x2 of 64x64), 16x16x32 bf16 MFMA.
__global__ __launch_bounds__(256) void gemm_kernel(
    const unsigned short* __restrict__ A, const unsigned short* __restrict__ Wt,
    const float* __restrict__ bias, float* __restrict__ out) {
    __shared__ char Alds[128 * 128];  // 128 rows x 64 bf16 (128B), XOR-swizzled 16B chunks
    __shared__ char Blds[128 * 128];

    // XCD-aware bijective swizzle (4096 blocks % 8 == 0)
    const int bid = blockIdx.x;
    const int swz = (bid & 7) * 512 + (bid >> 3);
    const int bm = swz >> 5;  // 0..127
    const int bn = swz & 31;  // 0..31

    const int t = threadIdx.x;
    const int lane = t & 63;
    const int wid = t >> 6;
    const int wm = wid >> 1, wn = wid & 1;
    const int lrow = lane & 15;
    const int lk = lane >> 4;  // 0..3

    // staging coords: thread t stages row r_in (+32 per issue), 16B chunk ch
    const int r_in = t >> 3;  // 0..31
    const int ch = t & 7;
    const int gch = ch ^ (r_in & 7);  // pre-swizzled global chunk

    const unsigned short* gA = A  + (size_t)(bm * 128 + r_in) * 1024 + gch * 8;
    const unsigned short* gB = Wt + (size_t)(bn * 128 + r_in) * 1024 + gch * 8;
    char* lA = Alds + r_in * 128 + ch * 16;
    char* lB = Blds + r_in * 128 + ch * 16;

    f32x4 acc[4][4];
    #pragma unroll
    for (int i = 0; i < 4; ++i)
        #pragma unroll
        for (int j = 0; j < 4; ++j) acc[i][j] = (f32x4)0.0f;

    const int swzr = lrow & 7;  // read-side swizzle (row&7 is lrow&7 for all frags)

    for (int kt = 0; kt < 16; ++kt) {
        #pragma unroll
        for (int i = 0; i < 4; ++i) {
            async_copy16(gA + (size_t)(i * 32) * 1024 + kt * 64, lA + i * 32 * 128);
            async_copy16(gB + (size_t)(i * 32) * 1024 + kt * 64, lB + i * 32 * 128);
        }
        __syncthreads();  // compiler emits vmcnt(0) before s_barrier

        #pragma unroll
        for (int ks = 0; ks < 2; ++ks) {
            bf16x8 af[4], bf[4];
            const int chunk = (ks * 4 + lk) ^ swzr;
            #pragma unroll
            for (int mi = 0; mi < 4; ++mi) {
                int row = wm * 64 + mi * 16 + lrow;
                af[mi] = *(const bf16x8*)(Alds + row * 128 + chunk * 16);
            }
            #pragma unroll
            for (int ni = 0; ni < 4; ++ni) {
                int nrow = wn * 64 + ni * 16 + lrow;
                bf[ni] = *(const bf16x8*)(Blds + nrow * 128 + chunk * 16);
            }
            #pragma unroll
            for (int mi = 0; mi < 4; ++mi)
                #pragma unroll
                for (int ni = 0; ni < 4; ++ni)
                    acc[mi][ni] = __builtin_amdgcn_mfma_f32_16x16x32_bf16(
                        af[mi], bf[ni], acc[mi][ni], 0, 0, 0);
        }
        if (kt != 15) __syncthreads();
    }

    // epilogue: bias + erf-gelu, fp32 store
    float bv[4];
    #pragma unroll
    for (int ni = 0; ni < 4; ++ni) bv[ni] = bias[bn * 128 + wn * 64 + ni * 16 + lrow];
    #pragma unroll
    for (int mi = 0; mi < 4; ++mi) {
        const int orow0 = bm * 128 + wm * 64 + mi * 16 + lk * 4;
        #pragma unroll
        for (int ni = 0; ni < 4; ++ni) {
            const int ocol = bn * 128 + wn * 64 + ni * 16 + lrow;
            #pragma unroll
            for (int r = 0; r < 4; ++r) {
                float y = acc[mi][ni][r] + bv[ni];
                float g = 0.5f * y * (1.0f + erff(y * 0.70710678118654752f));
                out[(size_t)(orow0 + r) * 4096 + ocol] = g;
            }
        }
    }
}

extern "C" void kernel_launch(void* const* d_in, const int* in_sizes, int n_in,
                              void* d_out, int out_size, void* d_ws, size_t ws_size,
                              hipStream_t stream) {
    const float* hidden = (const float*)d_in[0];   // [4,4096,1024]
    const float* gamma  = (const float*)d_in[1];   // [1024]
    const float* beta   = (const float*)d_in[2];   // [1024]
    const float* W      = (const float*)d_in[3];   // [1024,4096]
    const float* bias   = (const float*)d_in[4];   // [4096]
    float* out = (float*)d_out;                    // [16384,4096] fp32

    unsigned short* Abf = (unsigned short*)d_ws;                       // 32 MiB
    unsigned short* Wt  = (unsigned short*)((char*)d_ws + (size_t)16384 * 1024 * 2);  // 8 MiB

    ln_cast_kernel<<<16384, 256, 0, stream>>>(hidden, gamma, beta, Abf);
    wt_cast_kernel<<<dim3(128, 32), 256, 0, stream>>>(W, Wt);
    gemm_kernel<<<4096, 256, 0, stream>>>(Abf, Wt, bias, out);
}

// Round 2
// 223.925 us; speedup vs baseline: 1.0792x; 1.0792x over previous
//
#include <hip/hip_runtime.h>
#include <hip/hip_bf16.h>

typedef __attribute__((ext_vector_type(8))) short bf16x8;
typedef __attribute__((ext_vector_type(4))) float f32x4;

static __device__ __forceinline__ unsigned short f2bf(float f) {
    unsigned u = __builtin_bit_cast(unsigned, f);
    unsigned rounding = 0x7fffu + ((u >> 16) & 1u);
    u += rounding;
    return (unsigned short)(u >> 16);
}

static __device__ __forceinline__ void async_copy16(const void* g, void* l) {
    __builtin_amdgcn_global_load_lds(
        (const __attribute__((address_space(1))) unsigned int*)g,
        (__attribute__((address_space(3))) unsigned int*)l,
        16, 0, 0);
}

#define BARRIER() __builtin_amdgcn_s_barrier()
#define LGKM0()  do { asm volatile("s_waitcnt lgkmcnt(0)" ::: "memory"); \
                      __builtin_amdgcn_sched_barrier(0); } while (0)

// ---------------- LayerNorm (fp32) -> bf16 cast ----------------
__global__ __launch_bounds__(256) void ln_cast_kernel(
    const float* __restrict__ x, const float* __restrict__ gamma,
    const float* __restrict__ beta, unsigned short* __restrict__ out) {
    const int row = blockIdx.x;
    const int t = threadIdx.x;
    const float4 v = ((const float4*)(x + (size_t)row * 1024))[t];

    float s  = v.x + v.y + v.z + v.w;
    float ss = v.x * v.x + v.y * v.y + v.z * v.z + v.w * v.w;
    #pragma unroll
    for (int off = 32; off; off >>= 1) {
        s  += __shfl_down(s, off);
        ss += __shfl_down(ss, off);
    }
    __shared__ float red[8];
    const int wid = t >> 6, lane = t & 63;
    if (lane == 0) { red[wid] = s; red[wid + 4] = ss; }
    __syncthreads();
    if (t == 0) {
        float S  = red[0] + red[1] + red[2] + red[3];
        float SS = red[4] + red[5] + red[6] + red[7];
        float mu = S * (1.0f / 1024.0f);
        float var = SS * (1.0f / 1024.0f) - mu * mu;
        red[0] = mu;
        red[1] = rsqrtf(var + 1e-7f);
    }
    __syncthreads();
    const float mu = red[0], rs = red[1];
    const float4 g = ((const float4*)gamma)[t];
    const float4 b = ((const float4*)beta)[t];

    ushort4 pk;
    pk.x = f2bf((v.x - mu) * rs * g.x + b.x);
    pk.y = f2bf((v.y - mu) * rs * g.y + b.y);
    pk.z = f2bf((v.z - mu) * rs * g.z + b.z);
    pk.w = f2bf((v.w - mu) * rs * g.w + b.w);
    ((ushort4*)(out + (size_t)row * 1024))[t] = pk;
}

// ---------------- W [1024][4096] fp32 -> Wt [4096][1024] bf16 ----------------
__global__ __launch_bounds__(256) void wt_cast_kernel(
    const float* __restrict__ W, unsigned short* __restrict__ Wt) {
    __shared__ float tile[32][33];
    const int bx = blockIdx.x;
    const int by = blockIdx.y;
    const int tx = threadIdx.x & 31;
    const int ty = threadIdx.x >> 5;
    #pragma unroll
    for (int i = 0; i < 4; ++i) {
        int k = by * 32 + ty + i * 8;
        tile[ty + i * 8][tx] = W[(size_t)k * 4096 + bx * 32 + tx];
    }
    __syncthreads();
    #pragma unroll
    for (int i = 0; i < 4; ++i) {
        int n = bx * 32 + ty + i * 8;
        Wt[(size_t)n * 1024 + by * 32 + tx] = f2bf(tile[tx][ty + i * 8]);
    }
}

// ---------------- GEMM 256x256 tile, 8-phase, BK=64 ----------------
// A [16384][1024] bf16, Wt [4096][1024] bf16 (= W^T). out = gelu(A@Wt^T + b) fp32.
// 512 thr = 8 waves (2M x 4N), per-wave 128x64. LDS: 2 bufs x (A 32K + B 32K).
__global__ __launch_bounds__(512, 2) void gemm_kernel(
    const unsigned short* __restrict__ A, const unsigned short* __restrict__ Wt,
    const float* __restrict__ bias, float* __restrict__ out) {
    __shared__ char lds_mem[131072];

    const int bid = blockIdx.x;                  // 1024 blocks, %8==0 -> bijective
    const int swz = (bid & 7) * 128 + (bid >> 3);
    const int bm = swz >> 4;                     // 0..63
    const int bn = swz & 15;                     // 0..15

    const int t = threadIdx.x;
    const int lane = t & 63;
    const int wid = t >> 6;
    const int wm = wid >> 2;                     // 0..1
    const int wn = wid & 3;                      // 0..3
    const int lrow = lane & 15;
    const int lk = lane >> 4;                    // 0..3

    // staging: thread t -> row (t>>3)+64*issue, 16B chunk (t&7); src pre-swizzled
    const int srr = t >> 3;
    const int sch = t & 7;
    const int sgc = sch ^ (srr & 7);
    const unsigned short* gA = A  + (size_t)(bm * 256 + srr) * 1024 + sgc * 8;
    const unsigned short* gB = Wt + (size_t)(bn * 256 + srr) * 1024 + sgc * 8;
    const int lds_st = srr * 128 + sch * 16;

    auto stageA = [&](int kt, int mh, char* buf) {
        const unsigned short* g = gA + (size_t)(mh * 128) * 1024 + kt * 64;
        char* l = buf + mh * 16384 + lds_st;
        async_copy16(g, l);
        async_copy16(g + (size_t)64 * 1024, l + 64 * 128);
    };
    auto stageB = [&](int kt, int nh, char* buf) {
        const unsigned short* g = gB + (size_t)(nh * 128) * 1024 + kt * 64;
        char* l = buf + 32768 + nh * 16384 + lds_st;
        async_copy16(g, l);
        async_copy16(g + (size_t)64 * 1024, l + 64 * 128);
    };

    // read-side: frag row r, k-chunk kc -> LDS chunk kc ^ (r&7); r&7 == lane&7
    const int ck0 = ((lk) ^ (lane & 7)) * 16;
    const int ck1 = ((4 + lk) ^ (lane & 7)) * 16;
    const int aRow = (wm * 128 + lrow) * 128;            // + (mh*64+mi*16)*128
    const int bRow = 32768 + (wn * 64 + lrow) * 128;     // + (q*32+ni*16)*128

    f32x4 acc[2][2][4][2];
    #pragma unroll
    for (int mh = 0; mh < 2; ++mh)
        #pragma unroll
        for (int q = 0; q < 2; ++q)
            #pragma unroll
            for (int mi = 0; mi < 4; ++mi)
                #pragma unroll
                for (int ni = 0; ni < 2; ++ni) acc[mh][q][mi][ni] = (f32x4)0.0f;

    // prologue: kt0 fully, kt1 A-halves; keep kt1:A in flight (vmcnt 4)
    {
        char* b0p = lds_mem;
        char* b1p = lds_mem + 65536;
        stageA(0, 0, b0p); stageA(0, 1, b0p);
        stageB(0, 0, b0p); stageB(0, 1, b0p);
        stageA(1, 0, b1p); stageA(1, 1, b1p);
        asm volatile("s_waitcnt vmcnt(4)" ::: "memory");
        __builtin_amdgcn_sched_barrier(0);
        BARRIER();
    }

    const int NKT = 16;
    for (int kt = 0; kt < NKT; ++kt) {
        char* cbuf = lds_mem + ((kt & 1) << 16);
        char* nbuf = lds_mem + (((kt + 1) & 1) << 16);

        bf16x8 a0[4][2], a1[4][2], b0[2][2], b1[2][2];

        // ---- P1: read A-half0 (8) + B-q0 (4); stage kt+1:B0; MFMA (0,0)
        #pragma unroll
        for (int mi = 0; mi < 4; ++mi) {
            const char* p = cbuf + aRow + (mi * 16) * 128;
            a0[mi][0] = *(const bf16x8*)(p + ck0);
            a0[mi][1] = *(const bf16x8*)(p + ck1);
        }
        #pragma unroll
        for (int ni = 0; ni < 2; ++ni) {
            const char* p = cbuf + bRow + (ni * 16) * 128;
            b0[ni][0] = *(const bf16x8*)(p + ck0);
            b0[ni][1] = *(const bf16x8*)(p + ck1);
        }
        if (kt + 1 < NKT) stageB(kt + 1, 0, nbuf);
        BARRIER();
        LGKM0();
        __builtin_amdgcn_s_setprio(1);
        #pragma unroll
        for (int mi = 0; mi < 4; ++mi)
            #pragma unroll
            for (int ni = 0; ni < 2; ++ni) {
                acc[0][0][mi][ni] = __builtin_amdgcn_mfma_f32_16x16x32_bf16(a0[mi][0], b0[ni][0], acc[0][0][mi][ni], 0, 0, 0);
                acc[0][0][mi][ni] = __builtin_amdgcn_mfma_f32_16x16x32_bf16(a0[mi][1], b0[ni][1], acc[0][0][mi][ni], 0, 0, 0);
            }
        __builtin_amdgcn_s_setprio(0);
        BARRIER();

        // ---- P2: read B-q1 (4) + A-half1 (8); stage kt+1:B1; MFMA (0,1)
        #pragma unroll
        for (int ni = 0; ni < 2; ++ni) {
            const char* p = cbuf + bRow + ((32 + ni * 16)) * 128;
            b1[ni][0] = *(const bf16x8*)(p + ck0);
            b1[ni][1] = *(const bf16x8*)(p + ck1);
        }
        #pragma unroll
        for (int mi = 0; mi < 4; ++mi) {
            const char* p = cbuf + aRow + ((64 + mi * 16)) * 128;
            a1[mi][0] = *(const bf16x8*)(p + ck0);
            a1[mi][1] = *(const bf16x8*)(p + ck1);
        }
        if (kt + 1 < NKT) stageB(kt + 1, 1, nbuf);
        BARRIER();
        LGKM0();
        __builtin_amdgcn_s_setprio(1);
        #pragma unroll
        for (int mi = 0; mi < 4; ++mi)
            #pragma unroll
            for (int ni = 0; ni < 2; ++ni) {
                acc[0][1][mi][ni] = __builtin_amdgcn_mfma_f32_16x16x32_bf16(a0[mi][0], b1[ni][0], acc[0][1][mi][ni], 0, 0, 0);
                acc[0][1][mi][ni] = __builtin_amdgcn_mfma_f32_16x16x32_bf16(a0[mi][1], b1[ni][1], acc[0][1][mi][ni], 0, 0, 0);
            }
        __builtin_amdgcn_s_setprio(0);
        BARRIER();

        // ---- P3: no reads; stage kt+2:A0 into cbuf (reads of cbuf done); MFMA (1,1)
        if (kt + 2 < NKT) stageA(kt + 2, 0, cbuf);
        BARRIER();
        LGKM0();
        __builtin_amdgcn_s_setprio(1);
        #pragma unroll
        for (int mi = 0; mi < 4; ++mi)
            #pragma unroll
            for (int ni = 0; ni < 2; ++ni) {
                acc[1][1][mi][ni] = __builtin_amdgcn_mfma_f32_16x16x32_bf16(a1[mi][0], b1[ni][0], acc[1][1][mi][ni], 0, 0, 0);
                acc[1][1][mi][ni] = __builtin_amdgcn_mfma_f32_16x16x32_bf16(a1[mi][1], b1[ni][1], acc[1][1][mi][ni], 0, 0, 0);
            }
        __builtin_amdgcn_s_setprio(0);
        BARRIER();

        // ---- P4: no reads; stage kt+2:A1; MFMA (1,0); counted vmcnt; barrier
        if (kt + 2 < NKT) stageA(kt + 2, 1, cbuf);
        BARRIER();
        __builtin_amdgcn_s_setprio(1);
        #pragma unroll
        for (int mi = 0; mi < 4; ++mi)
            #pragma unroll
            for (int ni = 0; ni < 2; ++ni) {
                acc[1][0][mi][ni] = __builtin_amdgcn_mfma_f32_16x16x32_bf16(a1[mi][0], b0[ni][0], acc[1][0][mi][ni], 0, 0, 0);
                acc[1][0][mi][ni] = __builtin_amdgcn_mfma_f32_16x16x32_bf16(a1[mi][1], b0[ni][1], acc[1][0][mi][ni], 0, 0, 0);
            }
        __builtin_amdgcn_s_setprio(0);
        if (kt < NKT - 2) {
            asm volatile("s_waitcnt vmcnt(4)" ::: "memory");
        } else if (kt == NKT - 2) {
            asm volatile("s_waitcnt vmcnt(0)" ::: "memory");
        }
        __builtin_amdgcn_sched_barrier(0);
        BARRIER();
    }

    // ---- epilogue: bias + erf-gelu, fp32 store
    float bv[2][2];
    #pragma unroll
    for (int q = 0; q < 2; ++q)
        #pragma unroll
        for (int ni = 0; ni < 2; ++ni)
            bv[q][ni] = bias[bn * 256 + wn * 64 + q * 32 + ni * 16 + lrow];

    #pragma unroll
    for (int mh = 0; mh < 2; ++mh)
        #pragma unroll
        for (int q = 0; q < 2; ++q)
            #pragma unroll
            for (int mi = 0; mi < 4; ++mi)
                #pragma unroll
                for (int ni = 0; ni < 2; ++ni) {
                    const int row0 = bm * 256 + wm * 128 + mh * 64 + mi * 16 + lk * 4;
                    const int col  = bn * 256 + wn * 64 + q * 32 + ni * 16 + lrow;
                    #pragma unroll
                    for (int r = 0; r < 4; ++r) {
                        float y = acc[mh][q][mi][ni][r] + bv[q][ni];
                        float g = 0.5f * y * (1.0f + erff(y * 0.70710678118654752f));
                        out[(size_t)(row0 + r) * 4096 + col] = g;
                    }
                }
}

extern "C" void kernel_launch(void* const* d_in, const int* in_sizes, int n_in,
                              void* d_out, int out_size, void* d_ws, size_t ws_size,
                              hipStream_t stream) {
    const float* hidden = (const float*)d_in[0];
    const float* gamma  = (const float*)d_in[1];
    const float* beta   = (const float*)d_in[2];
    const float* W      = (const float*)d_in[3];
    const float* bias   = (const float*)d_in[4];
    float* out = (float*)d_out;

    unsigned short* Abf = (unsigned short*)d_ws;
    unsigned short* Wt  = (unsigned short*)((char*)d_ws + (size_t)16384 * 1024 * 2);

    ln_cast_kernel<<<16384, 256, 0, stream>>>(hidden, gamma, beta, Abf);
    wt_cast_kernel<<<dim3(128, 32), 256, 0, stream>>>(W, Wt);
    gemm_kernel<<<1024, 512, 0, stream>>>(Abf, Wt, bias, out);
}

// Round 3
// 207.052 us; speedup vs baseline: 1.1671x; 1.0815x over previous
//
#include <hip/hip_runtime.h>
#include <hip/hip_bf16.h>

typedef __attribute__((ext_vector_type(8))) short bf16x8;
typedef __attribute__((ext_vector_type(4))) float f32x4;

static __device__ __forceinline__ unsigned short f2bf(float f) {
    unsigned u = __builtin_bit_cast(unsigned, f);
    unsigned rounding = 0x7fffu + ((u >> 16) & 1u);
    u += rounding;
    return (unsigned short)(u >> 16);
}

static __device__ __forceinline__ void async_copy16(const void* g, void* l) {
    __builtin_amdgcn_global_load_lds(
        (const __attribute__((address_space(1))) unsigned int*)g,
        (__attribute__((address_space(3))) unsigned int*)l,
        16, 0, 0);
}

#define BARRIER() __builtin_amdgcn_s_barrier()
#define LGKM0()  do { asm volatile("s_waitcnt lgkmcnt(0)" ::: "memory"); \
                      __builtin_amdgcn_sched_barrier(0); } while (0)
#define VM0()    do { asm volatile("s_waitcnt vmcnt(0)" ::: "memory"); \
                      __builtin_amdgcn_sched_barrier(0); } while (0)

// fast erf-gelu via tanh approximation (|err| <= ~3e-3, threshold margin 0.07+)
static __device__ __forceinline__ float fast_gelu(float y) {
    float u = 0.7978845608028654f * y * (1.0f + 0.044715f * y * y);
    float au = fminf(fabsf(u), 9.0f);
    float e = __expf(-2.0f * au);
    float th = (1.0f - e) * __builtin_amdgcn_rcpf(1.0f + e);
    th = (u < 0.0f) ? -th : th;
    return 0.5f * y * (1.0f + th);
}

// ---------------- LayerNorm (fp32) -> bf16 cast ----------------
__global__ __launch_bounds__(256) void ln_cast_kernel(
    const float* __restrict__ x, const float* __restrict__ gamma,
    const float* __restrict__ beta, unsigned short* __restrict__ out) {
    const int row = blockIdx.x;
    const int t = threadIdx.x;
    const float4 v = ((const float4*)(x + (size_t)row * 1024))[t];

    float s  = v.x + v.y + v.z + v.w;
    float ss = v.x * v.x + v.y * v.y + v.z * v.z + v.w * v.w;
    #pragma unroll
    for (int off = 32; off; off >>= 1) {
        s  += __shfl_down(s, off);
        ss += __shfl_down(ss, off);
    }
    __shared__ float red[8];
    const int wid = t >> 6, lane = t & 63;
    if (lane == 0) { red[wid] = s; red[wid + 4] = ss; }
    __syncthreads();
    if (t == 0) {
        float S  = red[0] + red[1] + red[2] + red[3];
        float SS = red[4] + red[5] + red[6] + red[7];
        float mu = S * (1.0f / 1024.0f);
        float var = SS * (1.0f / 1024.0f) - mu * mu;
        red[0] = mu;
        red[1] = rsqrtf(var + 1e-7f);
    }
    __syncthreads();
    const float mu = red[0], rs = red[1];
    const float4 g = ((const float4*)gamma)[t];
    const float4 b = ((const float4*)beta)[t];

    ushort4 pk;
    pk.x = f2bf((v.x - mu) * rs * g.x + b.x);
    pk.y = f2bf((v.y - mu) * rs * g.y + b.y);
    pk.z = f2bf((v.z - mu) * rs * g.z + b.z);
    pk.w = f2bf((v.w - mu) * rs * g.w + b.w);
    ((ushort4*)(out + (size_t)row * 1024))[t] = pk;
}

// ---------------- W [1024][4096] fp32 -> Wt [4096][1024] bf16 ----------------
__global__ __launch_bounds__(256) void wt_cast_kernel(
    const float* __restrict__ W, unsigned short* __restrict__ Wt) {
    __shared__ float tile[32][33];
    const int bx = blockIdx.x;
    const int by = blockIdx.y;
    const int tx = threadIdx.x & 31;
    const int ty = threadIdx.x >> 5;
    #pragma unroll
    for (int i = 0; i < 4; ++i) {
        int k = by * 32 + ty + i * 8;
        tile[ty + i * 8][tx] = W[(size_t)k * 4096 + bx * 32 + tx];
    }
    __syncthreads();
    #pragma unroll
    for (int i = 0; i < 4; ++i) {
        int n = bx * 32 + ty + i * 8;
        Wt[(size_t)n * 1024 + by * 32 + tx] = f2bf(tile[tx][ty + i * 8]);
    }
}

// ---------------- GEMM 128x128 tile, BK=64, dbuf LDS 64KB, 2 blocks/CU ----------------
// T3-minimum schedule: stage(next) -> ds_read(cur)+MFMA -> vmcnt(0)+barrier.
// A [16384][1024] bf16, Wt [4096][1024] bf16. out = gelu(A@Wt^T + b) fp32.
__global__ __launch_bounds__(256, 2) void gemm_kernel(
    const unsigned short* __restrict__ A, const unsigned short* __restrict__ Wt,
    const float* __restrict__ bias, float* __restrict__ out) {
    __shared__ char lds_mem[65536];   // [2 bufs][A 16KB | B 16KB]

    const int bid = blockIdx.x;                 // 4096 blocks, %8==0 -> bijective
    const int swz = (bid & 7) * 512 + (bid >> 3);
    const int bm = swz >> 5;                    // 0..127
    const int bn = swz & 31;                    // 0..31

    const int t = threadIdx.x;
    const int lane = t & 63;
    const int wid = t >> 6;
    const int wm = wid >> 1, wn = wid & 1;
    const int lrow = lane & 15;
    const int lk = lane >> 4;                   // 0..3

    // staging: thread t -> row (t>>3)+32*i, 16B chunk (t&7); src pre-swizzled
    const int srr = t >> 3;                     // 0..31
    const int sch = t & 7;
    const int sgc = sch ^ (srr & 7);
    const unsigned short* gA = A  + (size_t)(bm * 128 + srr) * 1024 + sgc * 8;
    const unsigned short* gB = Wt + (size_t)(bn * 128 + srr) * 1024 + sgc * 8;
    const int lst = srr * 128 + sch * 16;

    auto stage = [&](int kt, char* buf) {
        #pragma unroll
        for (int i = 0; i < 4; ++i) {
            async_copy16(gA + (size_t)(i * 32) * 1024 + kt * 64, buf + i * 32 * 128 + lst);
            async_copy16(gB + (size_t)(i * 32) * 1024 + kt * 64, buf + 16384 + i * 32 * 128 + lst);
        }
    };

    // read-side swizzle: chunk c of frag-row r -> LDS 16B slot (c ^ (r&7)); r&7 == lrow&7
    const int ck0 = ((lk) ^ (lrow & 7)) * 16;
    const int ck1 = ((4 + lk) ^ (lrow & 7)) * 16;
    const int aBase = (wm * 64 + lrow) * 128;           // + mi*16*128
    const int bBase = 16384 + (wn * 64 + lrow) * 128;   // + ni*16*128

    f32x4 acc[4][4];
    #pragma unroll
    for (int i = 0; i < 4; ++i)
        #pragma unroll
        for (int j = 0; j < 4; ++j) acc[i][j] = (f32x4)0.0f;

    // prologue
    stage(0, lds_mem);
    VM0();
    BARRIER();

    const int NKT = 16;
    for (int kt = 0; kt < NKT; ++kt) {
        char* cbuf = lds_mem + ((kt & 1) << 15);
        char* nbuf = lds_mem + (((kt + 1) & 1) << 15);

        if (kt + 1 < NKT) stage(kt + 1, nbuf);   // issue next-tile loads FIRST

        bf16x8 af[4][2], bf[4][2];
        #pragma unroll
        for (int mi = 0; mi < 4; ++mi) {
            const char* p = cbuf + aBase + mi * 16 * 128;
            af[mi][0] = *(const bf16x8*)(p + ck0);
            af[mi][1] = *(const bf16x8*)(p + ck1);
        }
        #pragma unroll
        for (int ni = 0; ni < 4; ++ni) {
            const char* p = cbuf + bBase + ni * 16 * 128;
            bf[ni][0] = *(const bf16x8*)(p + ck0);
            bf[ni][1] = *(const bf16x8*)(p + ck1);
        }
        LGKM0();
        __builtin_amdgcn_s_setprio(1);
        #pragma unroll
        for (int mi = 0; mi < 4; ++mi)
            #pragma unroll
            for (int ni = 0; ni < 4; ++ni) {
                acc[mi][ni] = __builtin_amdgcn_mfma_f32_16x16x32_bf16(af[mi][0], bf[ni][0], acc[mi][ni], 0, 0, 0);
                acc[mi][ni] = __builtin_amdgcn_mfma_f32_16x16x32_bf16(af[mi][1], bf[ni][1], acc[mi][ni], 0, 0, 0);
            }
        __builtin_amdgcn_s_setprio(0);
        VM0();       // next-tile loads landed (latency hidden under the 32 MFMA)
        BARRIER();   // all waves' reads of cbuf done -> safe to restage it next iter
    }

    // ---- epilogue: bias + fast gelu, fp32 store
    float bv[4];
    #pragma unroll
    for (int ni = 0; ni < 4; ++ni) bv[ni] = bias[bn * 128 + wn * 64 + ni * 16 + lrow];
    #pragma unroll
    for (int mi = 0; mi < 4; ++mi) {
        const int row0 = bm * 128 + wm * 64 + mi * 16 + lk * 4;
        #pragma unroll
        for (int ni = 0; ni < 4; ++ni) {
            const int col = bn * 128 + wn * 64 + ni * 16 + lrow;
            #pragma unroll
            for (int r = 0; r < 4; ++r) {
                float y = acc[mi][ni][r] + bv[ni];
                out[(size_t)(row0 + r) * 4096 + col] = fast_gelu(y);
            }
        }
    }
}

extern "C" void kernel_launch(void* const* d_in, const int* in_sizes, int n_in,
                              void* d_out, int out_size, void* d_ws, size_t ws_size,
                              hipStream_t stream) {
    const float* hidden = (const float*)d_in[0];
    const float* gamma  = (const float*)d_in[1];
    const float* beta   = (const float*)d_in[2];
    const float* W      = (const float*)d_in[3];
    const float* bias   = (const float*)d_in[4];
    float* out = (float*)d_out;

    unsigned short* Abf = (unsigned short*)d_ws;
    unsigned short* Wt  = (unsigned short*)((char*)d_ws + (size_t)16384 * 1024 * 2);

    ln_cast_kernel<<<16384, 256, 0, stream>>>(hidden, gamma, beta, Abf);
    wt_cast_kernel<<<dim3(128, 32), 256, 0, stream>>>(W, Wt);
    gemm_kernel<<<4096, 256, 0, stream>>>(Abf, Wt, bias, out);
}